// Round 8
// baseline (193.463 us; speedup 1.0000x reference)
//
#include <hip/hip_runtime.h>
#include <hip/hip_bf16.h>
#include <stdint.h>

#define N_TOK 8192
#define D_K   1024
#define BM    256
#define BN    256
#define BK    64
#define NT    (D_K / BK)            // 16 K-tiles, 8 iterations x 2
#define HALF_E (128 * BK)           // 8192 elems = 16 KB per half-tile

typedef __attribute__((ext_vector_type(8))) short bf16x8;
typedef __attribute__((ext_vector_type(16))) float f32x16;

__global__ void zero_out_kernel(float* out) { out[0] = 0.0f; }

__device__ __forceinline__ unsigned short f32_to_bf16_rne(float x) {
  uint32_t u = __builtin_bit_cast(uint32_t, x);
  uint32_t r = (u >> 16) & 1u;
  u += 0x7fffu + r;
  return (unsigned short)(u >> 16);
}

__global__ void __launch_bounds__(256)
convert_kernel(const float* __restrict__ a, const float* __restrict__ b,
               ushort* __restrict__ oa, ushort* __restrict__ ob) {
  const size_t total4 = (size_t)N_TOK * D_K / 4;
  size_t i = (size_t)blockIdx.x * blockDim.x + threadIdx.x;
  size_t stride = (size_t)gridDim.x * blockDim.x;
  for (; i < total4; i += stride) {
    float4 va = ((const float4*)a)[i];
    float4 vb = ((const float4*)b)[i];
    ushort4 ua, ub;
    ua.x = f32_to_bf16_rne(va.x); ua.y = f32_to_bf16_rne(va.y);
    ua.z = f32_to_bf16_rne(va.z); ua.w = f32_to_bf16_rne(va.w);
    ub.x = f32_to_bf16_rne(vb.x); ub.y = f32_to_bf16_rne(vb.y);
    ub.z = f32_to_bf16_rne(vb.z); ub.w = f32_to_bf16_rne(vb.w);
    ((ushort4*)oa)[i] = ua;
    ((ushort4*)ob)[i] = ub;
  }
}

// Fused 256x256 bf16 MFMA GEMM + sigmoid-contrastive loss.
// 32x32x16 MFMA variant of the 8-phase schedule: 8 fat MFMA per phase,
// dbuf x 2 halves per operand (128 KB LDS), counted vmcnt(6) at p3/p7.
__global__ void __launch_bounds__(512, 2)
sigc_kernel(const ushort* __restrict__ A, const ushort* __restrict__ B,
            const int* __restrict__ labA, const int* __restrict__ labB,
            const float* __restrict__ scale_p, const float* __restrict__ bias_p,
            float* __restrict__ out) {
  // index: [op(A=0,B=1)<<2 | parity<<1 | half]
  __shared__ ushort sTile[8][HALF_E];     // 128 KB
  __shared__ int sLabA[BM];
  __shared__ int sLabB[BN];
  __shared__ float sPart[8];

  const int tid  = threadIdx.x;
  const int lane = tid & 63;
  const int wid  = tid >> 6;      // 0..7
  const int wr   = wid >> 2;      // 0..1 (M half: rows wr*128..)
  const int wc   = wid & 3;       // 0..3 (N quarter: cols wc*64..)
  const int l32  = lane & 31;
  const int hi   = lane >> 5;     // 0..1

  // T1: XCD-aware block swizzle (grid 1024, %8==0).
  const int bid  = (int)blockIdx.x;
  const int swzb = (bid & 7) * 128 + (bid >> 3);
  const int bRow = (swzb >> 5) * BM;
  const int bCol = (swzb & 31) * BN;

  if (tid < 256) sLabA[tid] = labA[bRow + tid];
  else           sLabB[tid - 256] = labB[bCol + (tid - 256)];

  // T2 (rule #21): linear LDS dest, XOR-swizzled global source column.
  auto stage = [&](const ushort* __restrict__ G, int gBase, int op,
                   int tile, int half, int ld) {
    const int par = tile & 1;
    ushort* d = &sTile[(op << 2) | (par << 1) | half][ld * 4096 + wid * 512];
    const int e    = ld * 4096 + tid * 8;
    const int row  = e >> 6;                    // 0..127 within half
    const int slot = (e >> 3) & 7;
    const int col  = (slot ^ (row & 7)) << 3;
    const ushort* g = G + (size_t)(gBase + half * 128 + row) * D_K
                        + tile * BK + col;
    __builtin_amdgcn_global_load_lds(
        (const __attribute__((address_space(1))) void*)g,
        (__attribute__((address_space(3))) void*)d, 16, 0, 0);
  };

  // A-frags for one 64-row half (2 mblocks x 4 k-chunks), 8 ds_read_b128.
  auto rdA = [&](int par, int mh, bf16x8 a[2][4]) {
    const ushort* p = sTile[(0 << 2) | (par << 1) | wr];
#pragma unroll
    for (int i = 0; i < 2; ++i) {
      const int r = (mh * 2 + i) * 32 + l32;
#pragma unroll
      for (int kk = 0; kk < 4; ++kk) {
        const int s = kk * 2 + hi;
        a[i][kk] = *(const bf16x8*)&p[r * BK + ((s ^ (r & 7)) << 3)];
      }
    }
  };
  // B-frags for one 32-col nblock (4 k-chunks), 4 ds_read_b128.
  auto rdB = [&](int par, int nb, bf16x8 b[4]) {
    const ushort* p = sTile[(1 << 2) | (par << 1) | (wc >> 1)];
    const int r = (wc & 1) * 64 + nb * 32 + l32;
#pragma unroll
    for (int kk = 0; kk < 4; ++kk) {
      const int s = kk * 2 + hi;
      b[kk] = *(const bf16x8*)&p[r * BK + ((s ^ (r & 7)) << 3)];
    }
  };

  f32x16 acc[4][2];
#pragma unroll
  for (int i = 0; i < 4; ++i)
#pragma unroll
    for (int j = 0; j < 2; ++j)
      acc[i][j] = (f32x16){0.f,0.f,0.f,0.f,0.f,0.f,0.f,0.f,
                           0.f,0.f,0.f,0.f,0.f,0.f,0.f,0.f};

  auto mmaq = [&](int mh, int nb, bf16x8 a[2][4], bf16x8 b[4]) {
    __builtin_amdgcn_s_setprio(1);
#pragma unroll
    for (int kk = 0; kk < 4; ++kk)
#pragma unroll
      for (int i = 0; i < 2; ++i)
        acc[mh * 2 + i][nb] = __builtin_amdgcn_mfma_f32_32x32x16_bf16(
            a[i][kk], b[kk], acc[mh * 2 + i][nb], 0, 0, 0);
    __builtin_amdgcn_s_setprio(0);
  };

  auto syncMid = [&]() {
    __builtin_amdgcn_s_barrier();
    asm volatile("s_waitcnt lgkmcnt(0)" ::: "memory");
    __builtin_amdgcn_sched_barrier(0);   // rule #18
  };
  auto syncEnd = [&]() {
    __builtin_amdgcn_s_barrier();
  };

  // Prologue: tile 0 fully (8 loads) + tile 1's [A.l0 x2, B x4] (6 loads).
  stage(A, bRow, 0, 0, 0, 0); stage(A, bRow, 0, 0, 0, 1);
  stage(A, bRow, 0, 0, 1, 0); stage(A, bRow, 0, 0, 1, 1);
  stage(B, bCol, 1, 0, 0, 0); stage(B, bCol, 1, 0, 0, 1);
  stage(B, bCol, 1, 0, 1, 0); stage(B, bCol, 1, 0, 1, 1);
  stage(A, bRow, 0, 1, 0, 0); stage(A, bRow, 0, 1, 1, 0);
  stage(B, bCol, 1, 1, 0, 0); stage(B, bCol, 1, 1, 0, 1);
  stage(B, bCol, 1, 1, 1, 0); stage(B, bCol, 1, 1, 1, 1);
  asm volatile("s_waitcnt vmcnt(6)" ::: "memory");   // tile 0 landed
  __syncthreads();

  bf16x8 af[2][4], bf0[4], bf1[4];

  for (int t2 = 0; t2 < NT / 2; ++t2) {
    const int e = 2 * t2, o = e + 1;
    const bool more = (t2 < NT / 2 - 1);

    // p0: (mh0, nb0) of tile e; stage A.l1(o).
    rdA(0, 0, af); rdB(0, 0, bf0);
    stage(A, bRow, 0, o, 0, 1); stage(A, bRow, 0, o, 1, 1);
    syncMid(); mmaq(0, 0, af, bf0); syncEnd();

    // p1: (mh0, nb1); stage A.l0(e+2).
    rdB(0, 1, bf1);
    if (more) { stage(A, bRow, 0, e + 2, 0, 0); stage(A, bRow, 0, e + 2, 1, 0); }
    syncMid(); mmaq(0, 1, af, bf1); syncEnd();

    // p2: (mh1, nb1); stage B.l0(e+2).
    rdA(0, 1, af);
    if (more) { stage(B, bCol, 1, e + 2, 0, 0); stage(B, bCol, 1, e + 2, 0, 1); }
    syncMid(); mmaq(1, 1, af, bf1); syncEnd();

    // p3: (mh1, nb0); stage B.l1(e+2); counted vmcnt -> tile o landed.
    if (more) { stage(B, bCol, 1, e + 2, 1, 0); stage(B, bCol, 1, e + 2, 1, 1); }
    if (more) asm volatile("s_waitcnt vmcnt(6)" ::: "memory");
    else      asm volatile("s_waitcnt vmcnt(0)" ::: "memory");
    __builtin_amdgcn_sched_barrier(0);
    syncMid(); mmaq(1, 0, af, bf0); syncEnd();

    // p4: (mh0, nb0) of tile o; stage A.l1(e+2).
    rdA(1, 0, af); rdB(1, 0, bf0);
    if (more) { stage(A, bRow, 0, e + 2, 0, 1); stage(A, bRow, 0, e + 2, 1, 1); }
    syncMid(); mmaq(0, 0, af, bf0); syncEnd();

    // p5: (mh0, nb1); stage A.l0(o+2).
    rdB(1, 1, bf1);
    if (more) { stage(A, bRow, 0, o + 2, 0, 0); stage(A, bRow, 0, o + 2, 1, 0); }
    syncMid(); mmaq(0, 1, af, bf1); syncEnd();

    // p6: (mh1, nb1); stage B.l0(o+2).
    rdA(1, 1, af);
    if (more) { stage(B, bCol, 1, o + 2, 0, 0); stage(B, bCol, 1, o + 2, 0, 1); }
    syncMid(); mmaq(1, 1, af, bf1); syncEnd();

    // p7: (mh1, nb0); stage B.l1(o+2); counted vmcnt -> tile e+2 landed.
    if (more) { stage(B, bCol, 1, o + 2, 1, 0); stage(B, bCol, 1, o + 2, 1, 1); }
    if (more) {
      asm volatile("s_waitcnt vmcnt(6)" ::: "memory");
      __builtin_amdgcn_sched_barrier(0);
    }
    syncMid(); mmaq(1, 0, af, bf0); syncEnd();
  }

  // Epilogue (exp2-form): softplus(t) = ln2*(max(u,0)+log2(1+2^-|u|)),
  // u = t*log2e; t = -label*logit; logit = s*d + b.
  const float L2E = 1.4426950408889634f;
  const float sl2e = scale_p[0] * L2E;
  const float bl2e = bias_p[0] * L2E;
  float loss = 0.0f;
#pragma unroll
  for (int mb = 0; mb < 4; ++mb) {
#pragma unroll
    for (int nb = 0; nb < 2; ++nb) {
      const int colL = sLabB[wc * 64 + nb * 32 + l32];
#pragma unroll
      for (int reg = 0; reg < 16; ++reg) {
        const int rowL =
            sLabA[wr * 128 + mb * 32 + (reg & 3) + 8 * (reg >> 2) + 4 * hi];
        const float u0 = fmaf(sl2e, acc[mb][nb][reg], bl2e);
        const float u = (rowL == colL) ? -u0 : u0;   // u = -label*logit*log2e
        loss += fmaxf(u, 0.0f) + log2f(1.0f + exp2f(-fabsf(u)));
      }
    }
  }

#pragma unroll
  for (int off = 32; off > 0; off >>= 1) loss += __shfl_down(loss, off, 64);
  if (lane == 0) sPart[wid] = loss;
  __syncthreads();
  if (tid == 0) {
    float s = 0.f;
#pragma unroll
    for (int w = 0; w < 8; ++w) s += sPart[w];
    atomicAdd(out, s * (0.6931471805599453f / (float)N_TOK));
  }
}

extern "C" void kernel_launch(void* const* d_in, const int* in_sizes, int n_in,
                              void* d_out, int out_size, void* d_ws, size_t ws_size,
                              hipStream_t stream) {
  const float* a  = (const float*)d_in[0];
  const float* b  = (const float*)d_in[1];
  const int*   la = (const int*)d_in[2];
  const int*   lb = (const int*)d_in[3];
  const float* sc = (const float*)d_in[4];
  const float* bi = (const float*)d_in[5];
  float* out = (float*)d_out;

  ushort* wa = (ushort*)d_ws;                       // bf16 A, 16 MB
  ushort* wb = wa + (size_t)N_TOK * D_K;            // bf16 B, 16 MB

  zero_out_kernel<<<1, 1, 0, stream>>>(out);
  convert_kernel<<<2048, 256, 0, stream>>>(a, b, wa, wb);
  const int grid = (N_TOK / BM) * (N_TOK / BN);     // 1024
  sigc_kernel<<<grid, 512, 0, stream>>>(wa, wb, la, lb, sc, bi, out);
}

// Round 9
// 171.526 us; speedup vs baseline: 1.1279x; 1.1279x over previous
//
#include <hip/hip_runtime.h>
#include <hip/hip_bf16.h>
#include <stdint.h>

#define N_TOK 8192
#define D_K   1024
#define BM    256
#define BN    256
#define BK    64
#define NT    (D_K / BK)            // 16 K-tiles, 8 iterations x 2
#define HALF_E (128 * BK)           // 8192 elems = 16 KB per half-tile

typedef __attribute__((ext_vector_type(8))) short bf16x8;
typedef __attribute__((ext_vector_type(4))) float f32x4;

__global__ void zero_out_kernel(float* out) { out[0] = 0.0f; }

__device__ __forceinline__ unsigned short f32_to_bf16_rne(float x) {
  uint32_t u = __builtin_bit_cast(uint32_t, x);
  uint32_t r = (u >> 16) & 1u;
  u += 0x7fffu + r;
  return (unsigned short)(u >> 16);
}

__global__ void __launch_bounds__(256)
convert_kernel(const float* __restrict__ a, const float* __restrict__ b,
               ushort* __restrict__ oa, ushort* __restrict__ ob) {
  const size_t total4 = (size_t)N_TOK * D_K / 4;
  size_t i = (size_t)blockIdx.x * blockDim.x + threadIdx.x;
  size_t stride = (size_t)gridDim.x * blockDim.x;
  for (; i < total4; i += stride) {
    float4 va = ((const float4*)a)[i];
    float4 vb = ((const float4*)b)[i];
    ushort4 ua, ub;
    ua.x = f32_to_bf16_rne(va.x); ua.y = f32_to_bf16_rne(va.y);
    ua.z = f32_to_bf16_rne(va.z); ua.w = f32_to_bf16_rne(va.w);
    ub.x = f32_to_bf16_rne(vb.x); ub.y = f32_to_bf16_rne(vb.y);
    ub.z = f32_to_bf16_rne(vb.z); ub.w = f32_to_bf16_rne(vb.w);
    ((ushort4*)oa)[i] = ua;
    ((ushort4*)ob)[i] = ub;
  }
}

// Fused 256x256 bf16 MFMA GEMM + sigmoid-contrastive loss.
// 16x16x32 8-phase schedule (R5 structure, 0 bank conflicts), plain
// launch_bounds (no spill), and 2-D XCD region mapping: each XCD owns an
// 8-row x 16-col block region (col-major within) so concurrent blocks
// share A/B panels in its private L2 (~6 MB working set vs 16 MB thrash).
__global__ void __launch_bounds__(512)
sigc_kernel(const ushort* __restrict__ A, const ushort* __restrict__ B,
            const int* __restrict__ labA, const int* __restrict__ labB,
            const float* __restrict__ scale_p, const float* __restrict__ bias_p,
            float* __restrict__ out) {
  // index: [op(A=0,B=1)<<2 | parity<<1 | half]
  __shared__ ushort sTile[8][HALF_E];     // 128 KB
  __shared__ int sLabA[BM];
  __shared__ int sLabB[BN];
  __shared__ float sPart[8];

  const int tid  = threadIdx.x;
  const int lane = tid & 63;
  const int wid  = tid >> 6;      // 0..7
  const int wr   = wid >> 2;      // 0..1 (M half: rows wr*128..)
  const int wc   = wid & 3;       // 0..3 (N quarter: cols wc*64..)
  const int lr   = lane & 15;
  const int sHi  = lane >> 4;     // 0..3

  // 2-D XCD region mapping (bijective): xcd = bid&7 owns block-rows
  // (xcd>>1)*8..+7 and block-cols (xcd&1)*16..+15; col-major within.
  const int bid  = (int)blockIdx.x;
  const int xcd  = bid & 7;
  const int ii   = bid >> 3;                    // 0..127
  const int rr   = (xcd >> 1) * 8 + (ii & 7);   // block-row 0..31
  const int cc   = (xcd & 1) * 16 + (ii >> 3);  // block-col 0..31
  const int bRow = rr * BM;
  const int bCol = cc * BN;

  if (tid < 256) sLabA[tid] = labA[bRow + tid];
  else           sLabB[tid - 256] = labB[bCol + (tid - 256)];

  // T2 (rule #21): linear LDS dest, XOR-swizzled global source column.
  auto stage = [&](const ushort* __restrict__ G, int gBase, int op,
                   int tile, int half, int ld) {
    const int par = tile & 1;
    ushort* d = &sTile[(op << 2) | (par << 1) | half][ld * 4096 + wid * 512];
    const int e    = ld * 4096 + tid * 8;
    const int row  = e >> 6;                    // 0..127 within half
    const int slot = (e >> 3) & 7;
    const int col  = (slot ^ (row & 7)) << 3;
    const ushort* g = G + (size_t)(gBase + half * 128 + row) * D_K
                        + tile * BK + col;
    __builtin_amdgcn_global_load_lds(
        (const __attribute__((address_space(1))) void*)g,
        (__attribute__((address_space(3))) void*)d, 16, 0, 0);
  };

  auto rdA = [&](int par, int ms, bf16x8 a[4][2]) {
    const ushort* p = sTile[(0 << 2) | (par << 1) | wr];
#pragma unroll
    for (int mf = 0; mf < 4; ++mf)
#pragma unroll
      for (int ks = 0; ks < 2; ++ks) {
        const int r = ms * 64 + mf * 16 + lr;
        const int s = ks * 4 + sHi;
        a[mf][ks] = *(const bf16x8*)&p[r * BK + ((s ^ (r & 7)) << 3)];
      }
  };
  auto rdB = [&](int par, int ns, bf16x8 b[2][2]) {
    const ushort* p = sTile[(1 << 2) | (par << 1) | (wc >> 1)];
#pragma unroll
    for (int nf = 0; nf < 2; ++nf)
#pragma unroll
      for (int ks = 0; ks < 2; ++ks) {
        const int r = (wc & 1) * 64 + ns * 32 + nf * 16 + lr;
        const int s = ks * 4 + sHi;
        b[nf][ks] = *(const bf16x8*)&p[r * BK + ((s ^ (r & 7)) << 3)];
      }
  };

  f32x4 acc[8][4];
#pragma unroll
  for (int i = 0; i < 8; ++i)
#pragma unroll
    for (int j = 0; j < 4; ++j) acc[i][j] = (f32x4){0.f, 0.f, 0.f, 0.f};

  auto mmaq = [&](int ms, int ns, bf16x8 a[4][2], bf16x8 b[2][2]) {
    __builtin_amdgcn_s_setprio(1);
#pragma unroll
    for (int ks = 0; ks < 2; ++ks)
#pragma unroll
      for (int mf = 0; mf < 4; ++mf)
#pragma unroll
        for (int nf = 0; nf < 2; ++nf)
          acc[ms * 4 + mf][ns * 2 + nf] =
              __builtin_amdgcn_mfma_f32_16x16x32_bf16(
                  a[mf][ks], b[nf][ks], acc[ms * 4 + mf][ns * 2 + nf], 0, 0, 0);
    __builtin_amdgcn_s_setprio(0);
  };

  auto syncMid = [&]() {
    __builtin_amdgcn_sched_barrier(0);
    __builtin_amdgcn_s_barrier();
    asm volatile("s_waitcnt lgkmcnt(0)" ::: "memory");
    __builtin_amdgcn_sched_barrier(0);   // rule #18
  };
  auto syncEnd = [&]() {
    __builtin_amdgcn_sched_barrier(0);
    __builtin_amdgcn_s_barrier();
  };

  // Prologue: tile 0 fully (8 loads) + tile 1's [A.l0 x2, B x4] (6 loads).
  stage(A, bRow, 0, 0, 0, 0); stage(A, bRow, 0, 0, 0, 1);
  stage(A, bRow, 0, 0, 1, 0); stage(A, bRow, 0, 0, 1, 1);
  stage(B, bCol, 1, 0, 0, 0); stage(B, bCol, 1, 0, 0, 1);
  stage(B, bCol, 1, 0, 1, 0); stage(B, bCol, 1, 0, 1, 1);
  stage(A, bRow, 0, 1, 0, 0); stage(A, bRow, 0, 1, 1, 0);
  stage(B, bCol, 1, 1, 0, 0); stage(B, bCol, 1, 1, 0, 1);
  stage(B, bCol, 1, 1, 1, 0); stage(B, bCol, 1, 1, 1, 1);
  asm volatile("s_waitcnt vmcnt(6)" ::: "memory");   // tile 0 landed
  __syncthreads();

  bf16x8 af[4][2], bf0[2][2], bf1[2][2];

  for (int t2 = 0; t2 < NT / 2; ++t2) {
    const int e = 2 * t2, o = e + 1;
    const bool more = (t2 < NT / 2 - 1);

    // p0: quadrant (0,0) of tile e; stage A.l1(o).
    rdA(0, 0, af); rdB(0, 0, bf0);
    stage(A, bRow, 0, o, 0, 1); stage(A, bRow, 0, o, 1, 1);
    syncMid(); mmaq(0, 0, af, bf0); syncEnd();

    // p1: (0,1); stage A.l0(e+2).
    rdB(0, 1, bf1);
    if (more) { stage(A, bRow, 0, e + 2, 0, 0); stage(A, bRow, 0, e + 2, 1, 0); }
    syncMid(); mmaq(0, 1, af, bf1); syncEnd();

    // p2: (1,1); stage B0(e+2).
    rdA(0, 1, af);
    if (more) { stage(B, bCol, 1, e + 2, 0, 0); stage(B, bCol, 1, e + 2, 0, 1); }
    syncMid(); mmaq(1, 1, af, bf1); syncEnd();

    // p3: (1,0); stage B1(e+2); counted vmcnt -> tile o fully landed.
    if (more) { stage(B, bCol, 1, e + 2, 1, 0); stage(B, bCol, 1, e + 2, 1, 1); }
    if (more) asm volatile("s_waitcnt vmcnt(6)" ::: "memory");
    else      asm volatile("s_waitcnt vmcnt(0)" ::: "memory");
    syncMid(); mmaq(1, 0, af, bf0); syncEnd();

    // p4: quadrant (0,0) of tile o; stage A.l1(e+2).
    rdA(1, 0, af); rdB(1, 0, bf0);
    if (more) { stage(A, bRow, 0, e + 2, 0, 1); stage(A, bRow, 0, e + 2, 1, 1); }
    syncMid(); mmaq(0, 0, af, bf0); syncEnd();

    // p5: (0,1); stage A.l0(o+2).
    rdB(1, 1, bf1);
    if (more) { stage(A, bRow, 0, o + 2, 0, 0); stage(A, bRow, 0, o + 2, 1, 0); }
    syncMid(); mmaq(0, 1, af, bf1); syncEnd();

    // p6: (1,1); stage B0(o+2).
    rdA(1, 1, af);
    if (more) { stage(B, bCol, 1, o + 2, 0, 0); stage(B, bCol, 1, o + 2, 0, 1); }
    syncMid(); mmaq(1, 1, af, bf1); syncEnd();

    // p7: (1,0); stage B1(o+2); counted vmcnt -> tile e+2 fully landed.
    if (more) { stage(B, bCol, 1, o + 2, 1, 0); stage(B, bCol, 1, o + 2, 1, 1); }
    if (more) asm volatile("s_waitcnt vmcnt(6)" ::: "memory");
    syncMid(); mmaq(1, 0, af, bf0); syncEnd();
  }

  // Epilogue (exp2-form): softplus contribution per pair =
  // ln2*(max(u,0)+log2(1+2^-|u|)), u = -label*logit*log2e.
  const float L2E = 1.4426950408889634f;
  const float sl2e = scale_p[0] * L2E;
  const float bl2e = bias_p[0] * L2E;
  float loss = 0.0f;
  const int cBase = lane & 15;
  const int rBase = (lane >> 4) * 4;
#pragma unroll
  for (int ms = 0; ms < 2; ++ms)
#pragma unroll
    for (int mf = 0; mf < 4; ++mf)
#pragma unroll
      for (int ns = 0; ns < 2; ++ns)
#pragma unroll
        for (int nf = 0; nf < 2; ++nf) {
          const int colL = sLabB[wc * 64 + ns * 32 + nf * 16 + cBase];
#pragma unroll
          for (int r = 0; r < 4; ++r) {
            const int rowL = sLabA[wr * 128 + ms * 64 + mf * 16 + rBase + r];
            const float u0 =
                fmaf(sl2e, acc[ms * 4 + mf][ns * 2 + nf][r], bl2e);
            const float u = (rowL == colL) ? -u0 : u0;
            loss += fmaxf(u, 0.0f) + log2f(1.0f + exp2f(-fabsf(u)));
          }
        }

#pragma unroll
  for (int off = 32; off > 0; off >>= 1) loss += __shfl_down(loss, off, 64);
  if (lane == 0) sPart[wid] = loss;
  __syncthreads();
  if (tid == 0) {
    float s = 0.f;
#pragma unroll
    for (int w = 0; w < 8; ++w) s += sPart[w];
    atomicAdd(out, s * (0.6931471805599453f / (float)N_TOK));
  }
}

extern "C" void kernel_launch(void* const* d_in, const int* in_sizes, int n_in,
                              void* d_out, int out_size, void* d_ws, size_t ws_size,
                              hipStream_t stream) {
  const float* a  = (const float*)d_in[0];
  const float* b  = (const float*)d_in[1];
  const int*   la = (const int*)d_in[2];
  const int*   lb = (const int*)d_in[3];
  const float* sc = (const float*)d_in[4];
  const float* bi = (const float*)d_in[5];
  float* out = (float*)d_out;

  ushort* wa = (ushort*)d_ws;                       // bf16 A, 16 MB
  ushort* wb = wa + (size_t)N_TOK * D_K;            // bf16 B, 16 MB

  zero_out_kernel<<<1, 1, 0, stream>>>(out);
  convert_kernel<<<2048, 256, 0, stream>>>(a, b, wa, wb);
  const int grid = (N_TOK / BM) * (N_TOK / BN);     // 1024
  sigc_kernel<<<grid, 512, 0, stream>>>(wa, wb, la, lb, sc, bi, out);
}